// Round 1
// baseline (54.463 us; speedup 1.0000x reference)
//
#include <hip/hip_runtime.h>

#define B_ 8
#define K_ 32
#define C_ 32
#define H_ 128
#define W_ 128
#define V_ (K_ * (C_ / 2))   // 512 vertices per batch

// ---------------------------------------------------------------------------
// Kernel 1: gather + trunc vertices.
// verts[b][v][0/1] = trunc(output[b, 2*c2 (+1), ind[b,k]] + centers[b,k,0/1])
// with v = k*16 + c2.
// ---------------------------------------------------------------------------
__global__ void gather_verts_kernel(const float* __restrict__ output,
                                    const int* __restrict__ ind,
                                    const float* __restrict__ centers,
                                    float* __restrict__ verts) {
    int idx = blockIdx.x * blockDim.x + threadIdx.x;   // [0, B_*V_)
    if (idx >= B_ * V_) return;
    int b  = idx / V_;
    int v  = idx % V_;
    int k  = v / (C_ / 2);
    int c2 = v % (C_ / 2);
    int pos = ind[b * K_ + k];
    float cx = centers[(b * K_ + k) * 2 + 0];
    float cy = centers[(b * K_ + k) * 2 + 1];
    float pvx = output[((size_t)(b * C_ + 2 * c2)     * (H_ * W_)) + pos];
    float pvy = output[((size_t)(b * C_ + 2 * c2 + 1) * (H_ * W_)) + pos];
    verts[idx * 2 + 0] = truncf(__fadd_rn(pvx, cx));
    verts[idx * 2 + 1] = truncf(__fadd_rn(pvy, cy));
}

// ---------------------------------------------------------------------------
// Kernel 2: rasterize one row per block (128 lanes = 128 pixels), even-odd
// crossing count over 512 edges, squared error vs target, block-sum to ws.
// The straddle branch is wave-uniform (depends only on row y).
// ---------------------------------------------------------------------------
__global__ void __launch_bounds__(W_) raster_mse_kernel(
        const float* __restrict__ verts,
        const float* __restrict__ target,
        float* __restrict__ bsums) {
    const int row = blockIdx.x & (H_ - 1);
    const int b   = blockIdx.x >> 7;          // /H_

    __shared__ float vx[V_];
    __shared__ float vy[V_];
    for (int i = threadIdx.x; i < V_; i += W_) {
        vx[i] = verts[((size_t)b * V_ + i) * 2 + 0];
        vy[i] = verts[((size_t)b * V_ + i) * 2 + 1];
    }
    __syncthreads();

    const float py = (float)row;
    const float px = (float)threadIdx.x;
    int cnt = 0;

    for (int e = 0; e < V_; ++e) {
        const int en = (e + 1) & (V_ - 1);
        const float y1 = vy[e];
        const float y2 = vy[en];
        const bool s1 = (y1 <= py);
        const bool s2 = (y2 <= py);
        if (s1 != s2) {                        // uniform across the block
            const float x1 = vx[e];
            const float x2 = vx[en];
            const float t    = __fdiv_rn(__fsub_rn(py, y1), __fsub_rn(y2, y1));
            const float xint = __fadd_rn(x1, __fmul_rn(t, __fsub_rn(x2, x1)));
            cnt += (px < xint) ? 1 : 0;
        }
    }

    const float inside = (cnt & 1) ? 255.0f : 0.0f;
    const float tgt = target[((size_t)b * H_ + row) * W_ + threadIdx.x];
    const float d = inside - tgt;
    float s = d * d;

    // deterministic block reduction: 2 waves of 64
    #pragma unroll
    for (int off = 32; off > 0; off >>= 1)
        s += __shfl_down(s, off, 64);
    __shared__ float wsum[2];
    if ((threadIdx.x & 63) == 0) wsum[threadIdx.x >> 6] = s;
    __syncthreads();
    if (threadIdx.x == 0) bsums[blockIdx.x] = wsum[0] + wsum[1];
}

// ---------------------------------------------------------------------------
// Kernel 3: deterministic finalize — sum B_*H_ block sums (double), compute
// denom from mask, write scalar.
// ---------------------------------------------------------------------------
__global__ void finalize_kernel(const float* __restrict__ bsums,
                                const float* __restrict__ mask,
                                float* __restrict__ out) {
    __shared__ double sd[256];
    double s = 0.0;
    for (int i = threadIdx.x; i < B_ * H_; i += 256)
        s += (double)bsums[i];
    sd[threadIdx.x] = s;
    __syncthreads();
    for (int off = 128; off > 0; off >>= 1) {
        if (threadIdx.x < off) sd[threadIdx.x] += sd[threadIdx.x + off];
        __syncthreads();
    }
    if (threadIdx.x == 0) {
        float msum = 0.0f;
        for (int i = 0; i < B_ * K_; ++i) msum += mask[i];
        const double denom = (double)msum * (double)C_ + 0.0001;
        out[0] = (float)(sd[0] / ((double)(H_ * W_)) / denom);
    }
}

extern "C" void kernel_launch(void* const* d_in, const int* in_sizes, int n_in,
                              void* d_out, int out_size, void* d_ws, size_t ws_size,
                              hipStream_t stream) {
    const float* output  = (const float*)d_in[0];
    const float* mask    = (const float*)d_in[1];
    const int*   ind     = (const int*)d_in[2];
    const float* target  = (const float*)d_in[3];
    const float* centers = (const float*)d_in[4];
    float* out = (float*)d_out;

    float* verts = (float*)d_ws;                    // B_*V_*2 floats = 32 KB
    float* bsums = verts + (size_t)B_ * V_ * 2;     // B_*H_ floats = 4 KB

    gather_verts_kernel<<<(B_ * V_ + 255) / 256, 256, 0, stream>>>(
        output, ind, centers, verts);

    raster_mse_kernel<<<B_ * H_, W_, 0, stream>>>(verts, target, bsums);

    finalize_kernel<<<1, 256, 0, stream>>>(bsums, mask, out);
}

// Round 2
// 41.521 us; speedup vs baseline: 1.3117x; 1.3117x over previous
//
#include <hip/hip_runtime.h>

#define B_ 8
#define K_ 32
#define C_ 32
#define H_ 128
#define W_ 128
#define V_ (K_ * (C_ / 2))   // 512 vertices per batch
#define NBLK (B_ * H_)       // 1024 blocks

// One fused kernel: per block = (batch, row).
//  1) gather this batch's 512 verts into LDS (4 verts/lane, L2-resident reads)
//  2) lane-per-edge: 4 edges/lane -> crossing cutoff c -> 128-bit parity mask
//  3) XOR-reduce masks across block -> row parity bitmap
//  4) per-pixel squared error vs target, block sum
//  5) fixed-point (2^20) u64 atomicAdd; last block (counter) computes the
//     final scalar, writes d_out, and resets acc/counter for the next replay.
__global__ void __launch_bounds__(W_) fused_poly_loss_kernel(
        const float* __restrict__ output,
        const float* __restrict__ mask,
        const int*   __restrict__ ind,
        const float* __restrict__ target,
        const float* __restrict__ centers,
        float* __restrict__ out,
        unsigned long long* __restrict__ acc,
        unsigned int* __restrict__ counter) {
    const int blk = blockIdx.x;
    const int b   = blk >> 7;          // / H_
    const int row = blk & (H_ - 1);
    const int l   = threadIdx.x;       // 0..127

    __shared__ float vx[V_];
    __shared__ float vy[V_];

    // ---- gather: lane l produces verts 4l..4l+3 (all same k = l>>2) ----
    {
        const int k   = l >> 2;
        const int pos = ind[b * K_ + k];
        const float cx = centers[(b * K_ + k) * 2 + 0];
        const float cy = centers[(b * K_ + k) * 2 + 1];
        const int v0 = 4 * l;
        const int c2base = v0 & 15;
        const float* ob = output + ((size_t)b * C_) * (H_ * W_) + pos;
        #pragma unroll
        for (int j = 0; j < 4; ++j) {
            const int c2 = c2base + j;
            const float pvx = ob[(size_t)(2 * c2)     * (H_ * W_)];
            const float pvy = ob[(size_t)(2 * c2 + 1) * (H_ * W_)];
            vx[v0 + j] = truncf(__fadd_rn(pvx, cx));
            vy[v0 + j] = truncf(__fadd_rn(pvy, cy));
        }
    }
    __syncthreads();

    // ---- lane-per-edge parity mask ----
    const float py = (float)row;
    unsigned long long mlo = 0ull, mhi = 0ull;
    {
        const int e0 = 4 * l;
        #pragma unroll
        for (int j = 0; j < 4; ++j) {
            const int e  = e0 + j;
            const int en = (e + 1) & (V_ - 1);
            const float y1 = vy[e];
            const float y2 = vy[en];
            const bool s1 = (y1 <= py);
            const bool s2 = (y2 <= py);
            if (s1 != s2) {            // dy != 0 guaranteed here
                const float x1 = vx[e];
                const float x2 = vx[en];
                const float t    = __fdiv_rn(__fsub_rn(py, y1), __fsub_rn(y2, y1));
                const float xint = __fadd_rn(x1, __fmul_rn(t, __fsub_rn(x2, x1)));
                // #\{ integer px in [0,128) : px < xint \} == clamp(ceil(xint),0,128)
                int c = (int)ceilf(xint);
                c = c < 0 ? 0 : (c > 128 ? 128 : c);
                unsigned long long lo, hi;
                if (c >= 64) {
                    lo = ~0ull;
                    hi = (c >= 128) ? ~0ull : ((1ull << (c - 64)) - 1ull);
                } else {
                    lo = (1ull << c) - 1ull;
                    hi = 0ull;
                }
                mlo ^= lo;
                mhi ^= hi;
            }
        }
    }
    // wave XOR reduce
    #pragma unroll
    for (int off = 32; off > 0; off >>= 1) {
        mlo ^= __shfl_xor(mlo, off, 64);
        mhi ^= __shfl_xor(mhi, off, 64);
    }
    __shared__ unsigned long long wlo[2], whi[2];
    __shared__ float fs[2];
    const int w = l >> 6;
    if ((l & 63) == 0) { wlo[w] = mlo; whi[w] = mhi; }
    __syncthreads();
    const unsigned long long lo = wlo[0] ^ wlo[1];
    const unsigned long long hi = whi[0] ^ whi[1];

    // ---- per-pixel MSE ----
    const int bit = (l < 64) ? (int)((lo >> l) & 1ull)
                             : (int)((hi >> (l - 64)) & 1ull);
    const float inside = bit ? 255.0f : 0.0f;
    const float tgt = target[((size_t)b * H_ + row) * W_ + l];
    const float d = __fsub_rn(inside, tgt);
    float s = __fmul_rn(d, d);
    #pragma unroll
    for (int off = 32; off > 0; off >>= 1) s += __shfl_down(s, off, 64);
    if ((l & 63) == 0) fs[w] = s;
    __syncthreads();

    __shared__ int lastflag;
    if (l == 0) {
        const float bs = fs[0] + fs[1];
        const unsigned long long fx =
            (unsigned long long)llrint((double)bs * 1048576.0);  // 2^20
        atomicAdd(acc, fx);
        __threadfence();
        const unsigned int old = atomicAdd(counter, 1u);
        lastflag = (old == (unsigned int)(NBLK - 1));
    }
    __syncthreads();   // also orders fs reads above vs. reuse below

    if (lastflag) {
        // block-parallel mask sum (256 floats)
        float ms = mask[l] + mask[l + 128];
        #pragma unroll
        for (int off = 32; off > 0; off >>= 1) ms += __shfl_down(ms, off, 64);
        if ((l & 63) == 0) fs[w] = ms;
        __syncthreads();
        if (l == 0) {
            const unsigned long long total = atomicAdd(acc, 0ull);
            const double sum = (double)total * (1.0 / 1048576.0);
            const float msum = fs[0] + fs[1];
            const float denomf = __fadd_rn(__fmul_rn(msum, (float)C_), 0.0001f);
            out[0] = (float)(sum / (double)(H_ * W_) / (double)denomf);
            // reset for next replay (deterministic: we are the only block left
            // touching acc/counter once counter hit NBLK-1)
            atomicExch(counter, 0u);
            atomicExch(acc, 0ull);
        }
    }
}

extern "C" void kernel_launch(void* const* d_in, const int* in_sizes, int n_in,
                              void* d_out, int out_size, void* d_ws, size_t ws_size,
                              hipStream_t stream) {
    const float* output  = (const float*)d_in[0];
    const float* mask    = (const float*)d_in[1];
    const int*   ind     = (const int*)d_in[2];
    const float* target  = (const float*)d_in[3];
    const float* centers = (const float*)d_in[4];
    float* out = (float*)d_out;

    unsigned long long* acc = (unsigned long long*)d_ws;
    unsigned int* counter   = (unsigned int*)((char*)d_ws + 8);

    // acc/counter start poisoned (0xAA) after the harness reset; zero them.
    hipMemsetAsync(d_ws, 0, 16, stream);

    fused_poly_loss_kernel<<<NBLK, W_, 0, stream>>>(
        output, mask, ind, target, centers, out, acc, counter);
}

// Round 5
// 14.327 us; speedup vs baseline: 3.8014x; 2.8980x over previous
//
#include <hip/hip_runtime.h>

#define B_ 8
#define K_ 32
#define C_ 32
#define H_ 128
#define W_ 128
#define V_ (K_ * (C_ / 2))        // 512 vertices per batch
#define RPB 4                     // rows per block
#define NBLK (B_ * H_ / RPB)      // 256 blocks

// ---------------------------------------------------------------------------
// Kernel 1: per block = (batch, 4 rows).
//  - gather batch's 512 verts into LDS (4 verts/lane, scattered L2 reads)
//  - per row: lane-per-edge (4 edges/lane) -> crossing cutoff c ->
//    128-bit pixel parity mask; XOR-reduce across block -> row bitmap
//  - per-pixel squared error vs target, accumulated over 4 rows
//  - block sum -> bsums[blk] (overwritten every call; no init needed)
// ---------------------------------------------------------------------------
__global__ void __launch_bounds__(W_) raster_kernel(
        const float* __restrict__ output,
        const int*   __restrict__ ind,
        const float* __restrict__ centers,
        const float* __restrict__ target,
        float* __restrict__ bsums) {
    const int blk = blockIdx.x;
    const int b   = blk >> 5;               // / (H_/RPB)
    const int r0  = (blk & 31) * RPB;
    const int l   = threadIdx.x;            // 0..127

    __shared__ float vx[V_];
    __shared__ float vy[V_];

    // ---- gather: lane l produces verts 4l..4l+3 (all same k = l>>2) ----
    {
        const int k   = l >> 2;
        const int pos = ind[b * K_ + k];
        const float cx = centers[(b * K_ + k) * 2 + 0];
        const float cy = centers[(b * K_ + k) * 2 + 1];
        const int v0  = 4 * l;
        const int c2b = v0 & 15;
        const float* ob = output + (size_t)b * C_ * (H_ * W_) + pos;
        #pragma unroll
        for (int j = 0; j < 4; ++j) {
            const int c2 = c2b + j;
            vx[v0 + j] = truncf(__fadd_rn(ob[(size_t)(2 * c2)     * (H_ * W_)], cx));
            vy[v0 + j] = truncf(__fadd_rn(ob[(size_t)(2 * c2 + 1) * (H_ * W_)], cy));
        }
    }
    __syncthreads();

    __shared__ unsigned long long wlo[2], whi[2];
    __shared__ float fs[2];
    const int w = l >> 6;
    float s = 0.0f;

    for (int rr = 0; rr < RPB; ++rr) {
        const int row = r0 + rr;
        const float py = (float)row;
        unsigned long long mlo = 0ull, mhi = 0ull;
        const int e0 = 4 * l;
        #pragma unroll
        for (int j = 0; j < 4; ++j) {
            const int e  = e0 + j;
            const int en = (e + 1) & (V_ - 1);
            const float y1 = vy[e];
            const float y2 = vy[en];
            if ((y1 <= py) != (y2 <= py)) {          // dy != 0 guaranteed
                const float x1 = vx[e];
                const float x2 = vx[en];
                const float t    = __fdiv_rn(__fsub_rn(py, y1), __fsub_rn(y2, y1));
                const float xint = __fadd_rn(x1, __fmul_rn(t, __fsub_rn(x2, x1)));
                // #{ integer px in [0,128) : px < xint } == clamp(ceil(xint),0,128)
                int c = (int)ceilf(xint);
                c = c < 0 ? 0 : (c > 128 ? 128 : c);
                unsigned long long lo, hi;
                if (c >= 64) {
                    lo = ~0ull;
                    hi = (c >= 128) ? ~0ull : ((1ull << (c - 64)) - 1ull);
                } else {
                    lo = (1ull << c) - 1ull;
                    hi = 0ull;
                }
                mlo ^= lo;
                mhi ^= hi;
            }
        }
        // XOR-reduce across the wave, then across the two waves
        #pragma unroll
        for (int off = 32; off > 0; off >>= 1) {
            mlo ^= __shfl_xor(mlo, off, 64);
            mhi ^= __shfl_xor(mhi, off, 64);
        }
        if ((l & 63) == 0) { wlo[w] = mlo; whi[w] = mhi; }
        __syncthreads();
        const unsigned long long lo = wlo[0] ^ wlo[1];
        const unsigned long long hi = whi[0] ^ whi[1];

        const int bit = (l < 64) ? (int)((lo >> l) & 1ull)
                                 : (int)((hi >> (l - 64)) & 1ull);
        const float inside = bit ? 255.0f : 0.0f;
        const float tgt = target[((size_t)b * H_ + row) * W_ + l];
        const float d = __fsub_rn(inside, tgt);
        s = __fadd_rn(s, __fmul_rn(d, d));
        __syncthreads();   // WAR: next row rewrites wlo/whi
    }

    #pragma unroll
    for (int off = 32; off > 0; off >>= 1) s += __shfl_down(s, off, 64);
    if ((l & 63) == 0) fs[w] = s;
    __syncthreads();
    if (l == 0) bsums[blk] = fs[0] + fs[1];
}

// ---------------------------------------------------------------------------
// Kernel 2: deterministic finalize — sum 256 block sums (double) + mask sum,
// write scalar. Everything overwritten each call; no state carried.
// ---------------------------------------------------------------------------
__global__ void __launch_bounds__(256) finalize_kernel(
        const float* __restrict__ bsums,
        const float* __restrict__ mask,
        float* __restrict__ out) {
    __shared__ double sd[256];
    __shared__ float  sm[256];
    sd[threadIdx.x] = (double)bsums[threadIdx.x];   // NBLK == 256
    sm[threadIdx.x] = mask[threadIdx.x];            // B_*K_ == 256
    __syncthreads();
    for (int off = 128; off > 0; off >>= 1) {
        if (threadIdx.x < off) {
            sd[threadIdx.x] += sd[threadIdx.x + off];
            sm[threadIdx.x] += sm[threadIdx.x + off];
        }
        __syncthreads();
    }
    if (threadIdx.x == 0) {
        const float denomf = __fadd_rn(__fmul_rn(sm[0], (float)C_), 0.0001f);
        out[0] = (float)(sd[0] / (double)(H_ * W_) / (double)denomf);
    }
}

extern "C" void kernel_launch(void* const* d_in, const int* in_sizes, int n_in,
                              void* d_out, int out_size, void* d_ws, size_t ws_size,
                              hipStream_t stream) {
    const float* output  = (const float*)d_in[0];
    const float* mask    = (const float*)d_in[1];
    const int*   ind     = (const int*)d_in[2];
    const float* target  = (const float*)d_in[3];
    const float* centers = (const float*)d_in[4];
    float* out = (float*)d_out;

    float* bsums = (float*)d_ws;   // 256 floats, fully overwritten every call

    raster_kernel<<<NBLK, W_, 0, stream>>>(output, ind, centers, target, bsums);
    finalize_kernel<<<1, 256, 0, stream>>>(bsums, mask, out);
}